// Round 1
// baseline (33965.967 us; speedup 1.0000x reference)
//
#include <hip/hip_runtime.h>
#include <cfloat>
#include <cstdint>

#define N_PTS 16384
#define KNN_K 16
#define KNN_TILE 512

// ---------------------------------------------------------------------------
// KNN: one wave per query point, per-lane top-16 (fp64 exact) + wave merge.
// Block = 256 threads = 4 waves = 4 queries. Grid = 4096.
// ---------------------------------------------------------------------------
__global__ __launch_bounds__(256) void knn_kernel(const float* __restrict__ pts,
                                                  int* __restrict__ knn_out) {
    __shared__ float sx[KNN_TILE], sy[KNN_TILE], sz[KNN_TILE];
    const int wave = threadIdx.x >> 6;
    const int lane = threadIdx.x & 63;
    const int qi = blockIdx.x * 4 + wave;
    const double qxd = (double)pts[qi * 3 + 0];
    const double qyd = (double)pts[qi * 3 + 1];
    const double qzd = (double)pts[qi * 3 + 2];

    double ld[16];
    int li[16];
#pragma unroll
    for (int s = 0; s < 16; ++s) { ld[s] = DBL_MAX; li[s] = 0x7fffffff; }
    double md = DBL_MAX; int mj = 0x7fffffff; int mslot = 0;

    for (int t0 = 0; t0 < N_PTS; t0 += KNN_TILE) {
        __syncthreads();
        for (int t = threadIdx.x; t < KNN_TILE; t += 256) {
            sx[t] = pts[(t0 + t) * 3 + 0];
            sy[t] = pts[(t0 + t) * 3 + 1];
            sz[t] = pts[(t0 + t) * 3 + 2];
        }
        __syncthreads();
#pragma unroll
        for (int m = 0; m < KNN_TILE / 64; ++m) {
            const int c = lane + m * 64;
            const int j = t0 + c;
            if (j == qi) continue;  // diagonal excluded (d=inf in reference)
            double dx = qxd - (double)sx[c];
            double dy = qyd - (double)sy[c];
            double dz = qzd - (double)sz[c];
            double dd = dx * dx + dy * dy + dz * dz;
            // accept if (dd,j) lex-less than current max (md,mj)
            if (dd < md || (dd == md && j < mj)) {
#pragma unroll
                for (int s = 0; s < 16; ++s)
                    if (s == mslot) { ld[s] = dd; li[s] = j; }
                // rescan for new max
                md = -1.0; mj = -1; mslot = 0;
#pragma unroll
                for (int s = 0; s < 16; ++s) {
                    bool g = (ld[s] > md) || (ld[s] == md && li[s] > mj);
                    if (g) { md = ld[s]; mj = li[s]; mslot = s; }
                }
            }
        }
    }

    // Wave merge: 16 rounds of extract-min over 64 lanes' local lists.
    const int out_base = qi * KNN_K;
    for (int r = 0; r < KNN_K; ++r) {
        double cd = DBL_MAX; int cj = 0x7fffffff; int cs = 0;
#pragma unroll
        for (int s = 0; s < 16; ++s) {
            bool l = (ld[s] < cd) || (ld[s] == cd && li[s] < cj);
            if (l) { cd = ld[s]; cj = li[s]; cs = s; }
        }
        double wd = cd; int wj = cj;
        for (int off = 32; off; off >>= 1) {
            double od = __shfl_xor(wd, off);
            int oj = __shfl_xor(wj, off);
            if (od < wd || (od == wd && oj < wj)) { wd = od; wj = oj; }
        }
        if (cd == wd && cj == wj) {  // unique winner lane consumes its slot
#pragma unroll
            for (int s = 0; s < 16; ++s)
                if (s == cs) { ld[s] = DBL_MAX; li[s] = 0x7fffffff; }
        }
        if (lane == 0) knn_out[out_base + r] = wj;
    }
}

// ---------------------------------------------------------------------------
// EdgeConv MLP + maxpool: one wave per point (lane = channel 0..63).
// h1 = relu([xi, xj-xi] @ ew1 + eb1); h2 = h1 @ ew2 + eb2; feat = max_k h2
// ---------------------------------------------------------------------------
__global__ __launch_bounds__(256) void edgeconv_kernel(
    const float* __restrict__ pts, const int* __restrict__ knn,
    const float* __restrict__ ew1, const float* __restrict__ eb1,
    const float* __restrict__ ew2, const float* __restrict__ eb2,
    float* __restrict__ feats) {
    __shared__ float w1[6 * 64], b1v[64], w2[64 * 64], b2v[64];
    for (int t = threadIdx.x; t < 6 * 64; t += 256) w1[t] = ew1[t];
    for (int t = threadIdx.x; t < 64; t += 256) { b1v[t] = eb1[t]; b2v[t] = eb2[t]; }
    for (int t = threadIdx.x; t < 64 * 64; t += 256) w2[t] = ew2[t];
    __syncthreads();

    const int wave = threadIdx.x >> 6, lane = threadIdx.x & 63;
    const int p = blockIdx.x * 4 + wave;
    const float xi = pts[p * 3], yi = pts[p * 3 + 1], zi = pts[p * 3 + 2];
    float acc = -FLT_MAX;
    for (int k = 0; k < KNN_K; ++k) {
        const int j = knn[p * 16 + k];
        const float xj = pts[j * 3], yj = pts[j * 3 + 1], zj = pts[j * 3 + 2];
        const float f0 = xi, f1 = yi, f2 = zi;
        const float f3 = xj - xi, f4 = yj - yi, f5 = zj - zi;
        float h1 = b1v[lane];
        h1 = fmaf(f0, w1[0 * 64 + lane], h1);
        h1 = fmaf(f1, w1[1 * 64 + lane], h1);
        h1 = fmaf(f2, w1[2 * 64 + lane], h1);
        h1 = fmaf(f3, w1[3 * 64 + lane], h1);
        h1 = fmaf(f4, w1[4 * 64 + lane], h1);
        h1 = fmaf(f5, w1[5 * 64 + lane], h1);
        h1 = fmaxf(h1, 0.0f);
        float h2 = b2v[lane];
        for (int d = 0; d < 64; ++d)
            h2 = fmaf(__shfl(h1, d), w2[d * 64 + lane], h2);
        acc = fmaxf(acc, h2);
    }
    feats[p * 64 + lane] = acc;
}

// ---------------------------------------------------------------------------
// FPS: single block, 1024 threads, P points per thread (n = 1024*P).
// d in fp64 registers (exact ordering), coords in fp32 registers.
// fi[0] = 0; then n_out-1 iterations of argmax + min-update.
// ---------------------------------------------------------------------------
template <int P>
__global__ __launch_bounds__(1024) void fps_kernel(const float* __restrict__ pts,
                                                   int n_out,
                                                   int* __restrict__ fi) {
    __shared__ double rd[16];
    __shared__ int rg[16];
    __shared__ float sel[3];
    const int tid = threadIdx.x;
    const int wave = tid >> 6, lane = tid & 63;

    float px[P], py[P], pz[P];
    double d[P];
#pragma unroll
    for (int q = 0; q < P; ++q) {
        const int g = tid + q * 1024;
        px[q] = pts[g * 3];
        py[q] = pts[g * 3 + 1];
        pz[q] = pts[g * 3 + 2];
    }
    {
        const double s0x = (double)pts[0], s0y = (double)pts[1], s0z = (double)pts[2];
#pragma unroll
        for (int q = 0; q < P; ++q) {
            double dx = (double)px[q] - s0x;
            double dy = (double)py[q] - s0y;
            double dz = (double)pz[q] - s0z;
            d[q] = dx * dx + dy * dy + dz * dz;
        }
    }
    if (tid == 0) fi[0] = 0;

    for (int it = 1; it < n_out; ++it) {
        // local argmax (lex: larger d, tie -> smaller global index)
        double m = -1.0; int mg = 0x7fffffff;
#pragma unroll
        for (int q = 0; q < P; ++q) {
            if (d[q] > m) { m = d[q]; mg = tid + q * 1024; }
        }
        // wave butterfly reduce
        for (int off = 32; off; off >>= 1) {
            double om = __shfl_xor(m, off);
            int og = __shfl_xor(mg, off);
            if (om > m || (om == m && og < mg)) { m = om; mg = og; }
        }
        if (lane == 0) { rd[wave] = m; rg[wave] = mg; }
        __syncthreads();
        if (wave == 0) {
            double m2 = (lane < 16) ? rd[lane] : -1.0;
            int g2 = (lane < 16) ? rg[lane] : 0x7fffffff;
            for (int off = 8; off; off >>= 1) {
                double om = __shfl_xor(m2, off);
                int og = __shfl_xor(g2, off);
                if (om > m2 || (om == m2 && og < g2)) { m2 = om; g2 = og; }
            }
            if (lane == 0) {
                fi[it] = g2;
                sel[0] = pts[g2 * 3];
                sel[1] = pts[g2 * 3 + 1];
                sel[2] = pts[g2 * 3 + 2];
            }
        }
        __syncthreads();
        const double sx = (double)sel[0], sy = (double)sel[1], sz = (double)sel[2];
#pragma unroll
        for (int q = 0; q < P; ++q) {
            double dx = (double)px[q] - sx;
            double dy = (double)py[q] - sy;
            double dz = (double)pz[q] - sz;
            double t = dx * dx + dy * dy + dz * dz;
            d[q] = (t < d[q]) ? t : d[q];
        }
    }
}

// ---------------------------------------------------------------------------
// Gathers: write sampled coords (exact bit copies) + compose original indices.
// ---------------------------------------------------------------------------
__global__ void gather0_kernel(const float* __restrict__ pts,
                               const int* __restrict__ fi0,
                               float* __restrict__ sp0) {
    int t = blockIdx.x * 256 + threadIdx.x;
    if (t >= 4096) return;
    int g = fi0[t];
    sp0[t * 3 + 0] = pts[g * 3 + 0];
    sp0[t * 3 + 1] = pts[g * 3 + 1];
    sp0[t * 3 + 2] = pts[g * 3 + 2];
}

__global__ void gather_next_kernel(const float* __restrict__ pts,
                                   const int* __restrict__ prev_orig,
                                   const int* __restrict__ fi, int S,
                                   float* __restrict__ sp,
                                   int* __restrict__ orig_out) {
    int t = blockIdx.x * 256 + threadIdx.x;
    if (t >= S) return;
    int f = fi[t];            // index into previous sp
    int g = prev_orig[f];     // original point index (== reference's argmin nn)
    orig_out[t] = g;
    sp[t * 3 + 0] = pts[g * 3 + 0];
    sp[t * 3 + 1] = pts[g * 3 + 1];
    sp[t * 3 + 2] = pts[g * 3 + 2];
}

// ---------------------------------------------------------------------------
// Per-scale MLP: lf = relu(sf @ mw1 + mb1) @ mw2 + mb2.
// Block = 256 threads, 16 points per block (weights re-read from L2, amortized).
// ---------------------------------------------------------------------------
__global__ __launch_bounds__(256) void mlp_kernel(
    const float* __restrict__ feats, const int* __restrict__ orig,
    const float* __restrict__ mw1, const float* __restrict__ mb1,
    const float* __restrict__ mw2, const float* __restrict__ mb2,
    float* __restrict__ out) {
    __shared__ float sfl[64], h1l[128];
    const int t = threadIdx.x;
    for (int pl = 0; pl < 16; ++pl) {
        const int p = blockIdx.x * 16 + pl;
        const int g = orig[p];
        if (t < 64) sfl[t] = feats[g * 64 + t];
        __syncthreads();
        if (t < 128) {
            float h = mb1[t];
            for (int dd = 0; dd < 64; ++dd)
                h = fmaf(sfl[dd], mw1[dd * 128 + t], h);
            h1l[t] = fmaxf(h, 0.0f);
        }
        __syncthreads();
        float o = mb2[t];
        for (int dd = 0; dd < 128; ++dd)
            o = fmaf(h1l[dd], mw2[dd * 256 + t], o);
        out[p * 256 + t] = o;
        __syncthreads();
    }
}

// ---------------------------------------------------------------------------
extern "C" void kernel_launch(void* const* d_in, const int* in_sizes, int n_in,
                              void* d_out, int out_size, void* d_ws, size_t ws_size,
                              hipStream_t stream) {
    const float* pts = (const float*)d_in[0];
    const float* ew1 = (const float*)d_in[1];
    const float* eb1 = (const float*)d_in[2];
    const float* ew2 = (const float*)d_in[3];
    const float* eb2 = (const float*)d_in[4];
    const float* mw1 = (const float*)d_in[5];  // (3,64,128)
    const float* mb1 = (const float*)d_in[6];  // (3,128)
    const float* mw2 = (const float*)d_in[7];  // (3,128,256)
    const float* mb2 = (const float*)d_in[8];  // (3,256)
    float* out = (float*)d_out;
    char* ws = (char*)d_ws;

    // workspace layout
    int* knn = (int*)(ws + 0);                        // 16384*16*4 = 1 MB
    float* feats = (float*)(ws + 1048576);            // 16384*64*4 = 4 MB
    int* fi0 = (int*)(ws + 5242880);                  // 4096 ints
    int* fi1 = (int*)(ws + 5259264);                  // 1024 ints
    int* fi2 = (int*)(ws + 5263360);                  // 256 ints
    int* orig1 = (int*)(ws + 5264384);                // 1024 ints
    int* orig2 = (int*)(ws + 5268480);                // 256 ints

    // output layout (floats)
    float* sp0 = out + 0;
    float* lf0 = out + 12288;
    float* sp1 = out + 1060864;
    float* lf1 = out + 1063936;
    float* sp2 = out + 1326080;
    float* lf2 = out + 1326848;

    knn_kernel<<<N_PTS / 4, 256, 0, stream>>>(pts, knn);
    edgeconv_kernel<<<N_PTS / 4, 256, 0, stream>>>(pts, knn, ew1, eb1, ew2, eb2, feats);

    // scale 0: FPS over 16384 -> 4096
    fps_kernel<16><<<1, 1024, 0, stream>>>(pts, 4096, fi0);
    gather0_kernel<<<16, 256, 0, stream>>>(pts, fi0, sp0);
    mlp_kernel<<<4096 / 16, 256, 0, stream>>>(feats, fi0, mw1 + 0 * 8192, mb1 + 0 * 128,
                                              mw2 + 0 * 32768, mb2 + 0 * 256, lf0);

    // scale 1: FPS over sp0 (4096) -> 1024
    fps_kernel<4><<<1, 1024, 0, stream>>>(sp0, 1024, fi1);
    gather_next_kernel<<<4, 256, 0, stream>>>(pts, fi0, fi1, 1024, sp1, orig1);
    mlp_kernel<<<1024 / 16, 256, 0, stream>>>(feats, orig1, mw1 + 1 * 8192, mb1 + 1 * 128,
                                              mw2 + 1 * 32768, mb2 + 1 * 256, lf1);

    // scale 2: FPS over sp1 (1024) -> 256
    fps_kernel<1><<<1, 1024, 0, stream>>>(sp1, 256, fi2);
    gather_next_kernel<<<1, 256, 0, stream>>>(pts, orig1, fi2, 256, sp2, orig2);
    mlp_kernel<<<256 / 16, 256, 0, stream>>>(feats, orig2, mw1 + 2 * 8192, mb1 + 2 * 128,
                                             mw2 + 2 * 32768, mb2 + 2 * 256, lf2);
}